// Round 25
// baseline (332.621 us; speedup 1.0000x reference)
//
#include <hip/hip_runtime.h>
#include <math.h>

#define NN 16384
#define KK 16
#define RPW 4                       // rows per scan wave
#define SW 4                        // scan waves per block
#define RPB (SW * RPW)              // 16 rows per block
#define CAP 512                     // per-row candidate buffer (u16 sorted idx)
#define NB 1024                     // x-sort buckets
#define NT 64                       // tiles of 256 sorted points
#define SCAN_BLOCKS (NN / RPB)      // 1024
#define MEGA_FILL 1024              // fill blocks inside mega (4096 waves)

typedef float f32x4 __attribute__((ext_vector_type(4)));
typedef unsigned long long u64;
typedef unsigned short u16;

// ---- d_ws layout (bytes): pts | perm | hist | cur | tileMM | nb  ----
#define WS_PTS   0
#define WS_PERM  (NN * 16)
#define WS_HIST  (WS_PERM + NN * 4)
#define WS_CUR   (WS_HIST + NB * 4)
#define WS_TMM   (WS_CUR + NB * 4)
#define WS_NB    (WS_TMM + NT * 8)
#define WS_NEED  (WS_NB + (size_t)NN * KK * 2)

__device__ __forceinline__ int xbucket(float x) {
    int b = (int)((x + 6.0f) * (NB / 12.0f));
    return b < 0 ? 0 : (b > NB - 1 ? NB - 1 : b);
}

// ============ k_sort: whole sort in ONE block (r22/r23-verified) ============
__global__ __launch_bounds__(1024) void k_sort(const float* __restrict__ nodes,
                                               float4* __restrict__ pts,
                                               int* __restrict__ perm,
                                               int* __restrict__ cur_g,
                                               float2* __restrict__ tmm_g) {
#pragma clang fp contract(off)
    __shared__ int sh[NB];
    __shared__ int shc[NB];
    const int t = threadIdx.x;                        // 0..1023
    sh[t] = 0;
    __syncthreads();
    for (int i = t; i < NN; i += 1024)
        atomicAdd(&sh[xbucket(nodes[3 * i])], 1);
    __syncthreads();
    const int h0 = sh[t];
    for (int o = 1; o < NB; o <<= 1) {                // r15-verified pattern
        const int v = (t >= o) ? sh[t - o] : 0;
        __syncthreads();
        sh[t] += v;
        __syncthreads();
    }
    shc[t] = sh[t] - h0;                              // exclusive prefix
    __syncthreads();
    for (int i = t; i < NN; i += 1024) {
        const float x = nodes[3 * i], y = nodes[3 * i + 1], z = nodes[3 * i + 2];
        const float sq = (x * x + y * y) + z * z;     // reference arithmetic
        const int pos = atomicAdd(&shc[xbucket(x)], 1);
        pts[pos] = make_float4(x, y, z, sq);
        perm[pos] = i;
    }
    __syncthreads();                                  // drains vmem before reads
    cur_g[t] = shc[t];          // inclusive bucket end (tile lookup, as r15-23)
    // bounds: 16 waves x 4 tiles each
    const int lane = t & 63, w = t >> 6;
    for (int tt = w; tt < NT; tt += 16) {
        float mn = INFINITY, mx = -INFINITY;
#pragma unroll
        for (int e = 0; e < 4; ++e) {
            const float x = pts[tt * 256 + e * 64 + lane].x;
            mn = fminf(mn, x); mx = fmaxf(mx, x);
        }
#pragma unroll
        for (int s = 1; s <= 32; s <<= 1) {
            mn = fminf(mn, __shfl_xor(mn, s));
            mx = fmaxf(mx, __shfl_xor(mx, s));
        }
        if (lane == 0) tmm_g[tt] = make_float2(mn, mx);
    }
}

// ---------------- verified helpers ----------------
__device__ __forceinline__ float bcastf(float v, int l) {
    return __int_as_float(__builtin_amdgcn_readlane(__float_as_int(v), l));
}
__device__ __forceinline__ bool lexless(float da, int ia, float db, int ib) {
    return (da < db) || ((da == db) && (ia < ib));
}
// r1-r6-verified distributed insert — overflow fallback only (~never hit).
__device__ __forceinline__ void insert_tile(bool rough, float d2, int j,
                                            float& ld, int& li,
                                            float& td, int& ti, float& td2u,
                                            int lane) {
#pragma clang fp contract(off)
    if (!__any(rough)) return;
    float dist = INFINITY;
    if (rough) dist = sqrtf(fmaxf(d2, 0.0f));
    bool done = false;
    while (true) {
        const bool pass = (!done) && rough && lexless(dist, j, td, ti);
        const u64 m = __ballot(pass);
        if (m == 0ull) break;
        const int src = __ffsll(m) - 1;
        const float dc = __shfl(dist, src);
        const int   ic = __shfl(j, src);
        if (lane == src) done = true;
        const bool gt = lexless(dc, ic, ld, li);
        const u64 gm = __ballot(gt);
        const int p = __ffsll(gm) - 1;
        const float pd = __shfl_up(ld, 1);
        const int   pi = __shfl_up(li, 1);
        if (gt) {
            if (lane == p) { ld = dc; li = ic; }
            else           { ld = pd; li = pi; }
        }
        td = __shfl(ld, 16);
        ti = __shfl(li, 16);
        td2u = td * td * 1.000001f;
    }
}

// ---------- scan body (r20-r23-verified machinery, byte-identical) ----------
__device__ __forceinline__ void scan_body(int sblock,
                                          const float4* __restrict__ pts,
                                          const int* __restrict__ perm,
                                          const int* __restrict__ cur,
                                          const float2* __restrict__ tmm_g,
                                          const float* __restrict__ nodes,
                                          float* __restrict__ out,
                                          u16* __restrict__ nbws) {
#pragma clang fp contract(off)
    const int lane = threadIdx.x & 63;
    const int wid  = threadIdx.x >> 6;
    const int tid  = threadIdx.x;
    const int rowBase = sblock * RPB;       // ORIGINAL row index, contiguous

    __shared__ float2 tmm[NT];
    __shared__ u16 buf[SW][RPW][CAP];       // 16 KB: candidate sorted-indices
    __shared__ u64 sel[SW][CAP];            // 16 KB: (distbits, orig idx) keys
    __shared__ int cnt[SW][RPW];

    if (tid < NT) tmm[tid] = tmm_g[tid];
    __syncthreads();

    float xs[RPW], ys[RPW], zs[RPW], ss[RPW];
    int tc[RPW];
#pragma unroll
    for (int r = 0; r < RPW; ++r) {
        const int row = rowBase + wid * RPW + r;
        xs[r] = nodes[3 * row];
        ys[r] = nodes[3 * row + 1];
        zs[r] = nodes[3 * row + 2];
        ss[r] = (xs[r] * xs[r] + ys[r] * ys[r]) + zs[r] * zs[r];
        int t = (cur[xbucket(xs[r])] - 1) >> 8;
        t = t - 1; t = t < 0 ? 0 : (t > NT - 3 ? NT - 3 : t);
        tc[r] = t;
    }

    // ===== tau phase: 3 local tiles per row (768 actual candidates) =====
    float rm[RPW];
#pragma unroll
    for (int r = 0; r < RPW; ++r) rm[r] = INFINITY;
#pragma unroll
    for (int r = 0; r < RPW; ++r) {
        for (int tt = 0; tt < 3; ++tt) {
            const int tb = (tc[r] + tt) * 256;
            const float4 q0 = pts[tb + lane];
            const float4 q1 = pts[tb + 64 + lane];
            const float4 q2 = pts[tb + 128 + lane];
            const float4 q3 = pts[tb + 192 + lane];
            const float d0 = (ss[r] + q0.w) - 2.0f * fmaf(zs[r], q0.z, fmaf(ys[r], q0.y, xs[r] * q0.x));
            const float d1 = (ss[r] + q1.w) - 2.0f * fmaf(zs[r], q1.z, fmaf(ys[r], q1.y, xs[r] * q1.x));
            const float d2 = (ss[r] + q2.w) - 2.0f * fmaf(zs[r], q2.z, fmaf(ys[r], q2.y, xs[r] * q2.x));
            const float d3 = (ss[r] + q3.w) - 2.0f * fmaf(zs[r], q3.z, fmaf(ys[r], q3.y, xs[r] * q3.x));
            rm[r] = fminf(rm[r], fminf(fminf(d0, d1), fminf(d2, d3)));
        }
    }
    // r12-verified bitonic sort of 64 lane-mins; tau = 17th (conservative).
    float sv[RPW];
#pragma unroll
    for (int r = 0; r < RPW; ++r) sv[r] = rm[r];
#pragma unroll
    for (int k = 2; k <= 64; k <<= 1) {
#pragma unroll
        for (int j = k >> 1; j >= 1; j >>= 1) {
            const bool keepmin = (((lane & j) == 0) == ((lane & k) == 0));
#pragma unroll
            for (int r = 0; r < RPW; ++r) {
                const float o = __shfl_xor(sv[r], j);
                sv[r] = keepmin ? fminf(sv[r], o) : fmaxf(sv[r], o);
            }
        }
    }
    float tau[RPW];
#pragma unroll
    for (int r = 0; r < RPW; ++r)   // *1.000002+eps: sqrt-tie-collapse guard
        tau[r] = fmaxf(bcastf(sv[r], 16), 0.0f) * 1.000002f + 1e-30f;

    if (lane < RPW) cnt[wid][lane] = 0;
    asm volatile("s_waitcnt lgkmcnt(0)" ::: "memory");

    // ===== screen pass: AABB-pruned tiles; append u16 sorted-idx only =====
    for (int t = 0; t < NT; ++t) {
        const float2 mm = tmm[t];
        bool kp[RPW]; bool anyk = false;
#pragma unroll
        for (int r = 0; r < RPW; ++r) {
            const float dx = fmaxf(fmaxf(mm.x - xs[r], xs[r] - mm.y), 0.0f);
            kp[r] = (dx * dx <= tau[r] * 1.00001f + 5e-5f);   // fp32-slack prune
            anyk |= kp[r];
        }
        if (!anyk) continue;        // wave-uniform skip
        const int base = t * 256;
        const float4 q0 = pts[base + lane];
        const float4 q1 = pts[base + 64 + lane];
        const float4 q2 = pts[base + 128 + lane];
        const float4 q3 = pts[base + 192 + lane];
#pragma unroll
        for (int r = 0; r < RPW; ++r) {
            if (!kp[r]) continue;
            const float d0 = (ss[r] + q0.w) - 2.0f * fmaf(zs[r], q0.z, fmaf(ys[r], q0.y, xs[r] * q0.x));
            const float d1 = (ss[r] + q1.w) - 2.0f * fmaf(zs[r], q1.z, fmaf(ys[r], q1.y, xs[r] * q1.x));
            const float d2 = (ss[r] + q2.w) - 2.0f * fmaf(zs[r], q2.z, fmaf(ys[r], q2.y, xs[r] * q2.x));
            const float d3 = (ss[r] + q3.w) - 2.0f * fmaf(zs[r], q3.z, fmaf(ys[r], q3.y, xs[r] * q3.x));
            const bool p0 = d0 <= tau[r], p1 = d1 <= tau[r];
            const bool p2 = d2 <= tau[r], p3 = d3 <= tau[r];
            if (p0 | p1 | p2 | p3) {
                if (p0) { const int o = atomicAdd(&cnt[wid][r], 1);
                          if (o < CAP) buf[wid][r][o] = (u16)(base + lane); }
                if (p1) { const int o = atomicAdd(&cnt[wid][r], 1);
                          if (o < CAP) buf[wid][r][o] = (u16)(base + 64 + lane); }
                if (p2) { const int o = atomicAdd(&cnt[wid][r], 1);
                          if (o < CAP) buf[wid][r][o] = (u16)(base + 128 + lane); }
                if (p3) { const int o = atomicAdd(&cnt[wid][r], 1);
                          if (o < CAP) buf[wid][r][o] = (u16)(base + 192 + lane); }
            }
        }
    }
    asm volatile("s_waitcnt lgkmcnt(0)" ::: "memory");

    // ===== select: recompute d2, exact lex-(dist, orig idx) rank =====
#pragma unroll
    for (int r = 0; r < RPW; ++r) {
        const int C = cnt[wid][r];
        const int row = rowBase + wid * RPW + r;
        if (C <= CAP) {                 // C >= 17 guaranteed (tau subset bound)
            for (int e = lane; e < C; e += 64) {
                const int si = (int)buf[wid][r][e];
                const float4 q = pts[si];
                const float dd = (ss[r] + q.w) - 2.0f * fmaf(zs[r], q.z, fmaf(ys[r], q.y, xs[r] * q.x));
                const float dist = sqrtf(fmaxf(dd, 0.0f));      // IEEE, as ref
                sel[wid][e] = (((u64)__float_as_uint(dist)) << 32) | (unsigned)perm[si];
            }
            asm volatile("s_waitcnt lgkmcnt(0) vmcnt(0)" ::: "memory");
            for (int e = lane; e < C; e += 64) {
                const u64 my = sel[wid][e];
                int rk = 0;
                for (int c = 0; c < C; ++c)
                    rk += (sel[wid][c] < my) ? 1 : 0;   // orig idx unique
                if (rk >= 1 && rk <= KK) {
                    if (nbws) nbws[(size_t)row * KK + rk - 1] = (u16)(my & 0xffffu);
                    else      out[(size_t)row * NN + (int)(my & 0xffffffffu)] = 1.0f;
                }
            }
            asm volatile("s_waitcnt lgkmcnt(0)" ::: "memory");  // before sel reuse
        } else {
            // Pathological overflow: verified full-scan insert, orig-idx keys.
            float ld = INFINITY; int li = 0x7fffffff;
            float td = INFINITY; int ti = 0x7fffffff; float t2 = INFINITY;
            for (int tt = 0; tt < NN / 64; ++tt) {
                const int j = tt * 64 + lane;
                const float4 q = pts[j];
                const int oi = perm[j];
                const float dd = (ss[r] + q.w) - 2.0f * fmaf(zs[r], q.z, fmaf(ys[r], q.y, xs[r] * q.x));
                insert_tile(dd <= t2, dd, oi, ld, li, td, ti, t2, lane);
            }
            if (lane >= 1 && lane <= KK) {
                if (nbws) nbws[(size_t)row * KK + lane - 1] = (u16)li;
                else      out[(size_t)row * NN + li] = 1.0f;
            }
        }
    }
}

// ===== k_mega: 1024 scan + 1024 fill blocks. Type selector = (b & 8):
// blocks 0-7 of every 16 -> scan, 8-15 -> fill. With blockIdx%8 -> XCD
// round-robin, BOTH types cover all 8 XCDs uniformly (r23's b&1 parity put
// every scan block on even residues = half the XCDs -> scan double-queued,
// ~2x stretch; r24 showed mega was scan-bound). 4096+4096 waves = capacity.
__global__ __launch_bounds__(256) void k_mega(const float4* __restrict__ pts,
                                              const int* __restrict__ perm,
                                              const int* __restrict__ cur,
                                              const float2* __restrict__ tmm_g,
                                              const float* __restrict__ nodes,
                                              float* __restrict__ out,
                                              u16* __restrict__ nbws) {
    const int b = blockIdx.x;
    const int idx = (b >> 4) * 8 + (b & 7);           // [0, 1024) per type
    if (b & 8) {
        // ---- fill block: whole output, NT streaming (r19-r23-verified) ----
        const int tid = idx * 256 + threadIdx.x;
        const int nthreads = MEGA_FILL * 256;
        f32x4* ob = (f32x4*)out;
        const f32x4 z4 = {0.f, 0.f, 0.f, 0.f};
#pragma unroll 4
        for (int k = 0; k < (NN * (NN / 4)) / nthreads; ++k)   // 256 iterations
            __builtin_nontemporal_store(z4, ob + (size_t)k * nthreads + tid);
    } else {
        scan_body(idx, pts, perm, cur, tmm_g, nodes, nullptr, nbws);
    }
}

// ============ k_ones: stamp the 262144 ones (stream-ordered after mega) =====
__global__ __launch_bounds__(256) void ones_kernel(const u16* __restrict__ nbws,
                                                   float* __restrict__ out) {
    const int t = blockIdx.x * 256 + threadIdx.x;     // t < NN*KK
    const int row = t >> 4;
    out[(size_t)row * NN + nbws[t]] = 1.0f;
}

// ---------------- fallback (ws too small): serial r20 path ----------------
__global__ __launch_bounds__(256) void fill_zero_full(f32x4* __restrict__ ob) {
    const int tid = blockIdx.x * 256 + threadIdx.x;
    const int nthreads = 2048 * 256;
    const f32x4 z4 = {0.f, 0.f, 0.f, 0.f};
#pragma unroll 4
    for (int k = 0; k < (NN * (NN / 4)) / nthreads; ++k)
        __builtin_nontemporal_store(z4, ob + (size_t)k * nthreads + tid);
}

__global__ __launch_bounds__(256) void knn_scan_direct(const float4* __restrict__ pts,
                                                       const int* __restrict__ perm,
                                                       const int* __restrict__ cur,
                                                       const float2* __restrict__ tmm_g,
                                                       const float* __restrict__ nodes,
                                                       float* __restrict__ out) {
    scan_body(blockIdx.x, pts, perm, cur, tmm_g, nodes, out, nullptr);
}

extern "C" void kernel_launch(void* const* d_in, const int* in_sizes, int n_in,
                              void* d_out, int out_size, void* d_ws, size_t ws_size,
                              hipStream_t stream) {
    const float* nodes = (const float*)d_in[0];
    float* out = (float*)d_out;
    (void)in_sizes; (void)n_in; (void)out_size;

    char* ws = (char*)d_ws;
    float4* pts  = (float4*)(ws + WS_PTS);
    int*    perm = (int*)   (ws + WS_PERM);
    int*    cur  = (int*)   (ws + WS_CUR);
    float2* tmm  = (float2*)(ws + WS_TMM);
    u16*    nbws = (u16*)   (ws + WS_NB);

    hipLaunchKernelGGL(k_sort, dim3(1), dim3(1024), 0, stream,
                       nodes, pts, perm, cur, tmm);

    if (ws_size >= WS_NEED) {
        hipLaunchKernelGGL(k_mega, dim3(2 * SCAN_BLOCKS), dim3(256), 0, stream,
                           pts, perm, cur, tmm, nodes, out, nbws);
        hipLaunchKernelGGL(ones_kernel, dim3(NN * KK / 256), dim3(256), 0, stream,
                           nbws, out);
    } else {
        hipLaunchKernelGGL(fill_zero_full, dim3(2048), dim3(256), 0, stream,
                           (f32x4*)out);
        hipLaunchKernelGGL(knn_scan_direct, dim3(SCAN_BLOCKS), dim3(256), 0, stream,
                           pts, perm, cur, tmm, nodes, out);
    }
}

// Round 26
// 261.914 us; speedup vs baseline: 1.2700x; 1.2700x over previous
//
#include <hip/hip_runtime.h>
#include <math.h>

#define NN 16384
#define KK 16
#define RPW 4                       // rows per scan wave
#define SW 4                        // scan waves per block
#define RPB (SW * RPW)              // 16 rows per block
#define CAP 512                     // per-row candidate buffer (u16 sorted idx)
#define NB 1024                     // x-sort buckets
#define NT 64                       // tiles of 256 sorted points
#define SCAN_BLOCKS (NN / RPB)      // 1024
#define MEGA_FILL 1024              // fill blocks inside mega (4096 waves)

typedef float f32x4 __attribute__((ext_vector_type(4)));
typedef unsigned long long u64;
typedef unsigned short u16;

// ---- d_ws layout (bytes): pts | perm | hist | cur | tileMM | nb  ----
#define WS_PTS   0
#define WS_PERM  (NN * 16)
#define WS_HIST  (WS_PERM + NN * 4)
#define WS_CUR   (WS_HIST + NB * 4)
#define WS_TMM   (WS_CUR + NB * 4)
#define WS_NB    (WS_TMM + NT * 8)
#define WS_NEED  (WS_NB + (size_t)NN * KK * 2)

__device__ __forceinline__ int xbucket(float x) {
    int b = (int)((x + 6.0f) * (NB / 12.0f));
    return b < 0 ? 0 : (b > NB - 1 ? NB - 1 : b);
}

// ============ k_sort: whole sort in ONE block (r22/r23-verified) ============
__global__ __launch_bounds__(1024) void k_sort(const float* __restrict__ nodes,
                                               float4* __restrict__ pts,
                                               int* __restrict__ perm,
                                               int* __restrict__ cur_g,
                                               float2* __restrict__ tmm_g) {
#pragma clang fp contract(off)
    __shared__ int sh[NB];
    __shared__ int shc[NB];
    const int t = threadIdx.x;                        // 0..1023
    sh[t] = 0;
    __syncthreads();
    for (int i = t; i < NN; i += 1024)
        atomicAdd(&sh[xbucket(nodes[3 * i])], 1);
    __syncthreads();
    const int h0 = sh[t];
    for (int o = 1; o < NB; o <<= 1) {                // r15-verified pattern
        const int v = (t >= o) ? sh[t - o] : 0;
        __syncthreads();
        sh[t] += v;
        __syncthreads();
    }
    shc[t] = sh[t] - h0;                              // exclusive prefix
    __syncthreads();
    for (int i = t; i < NN; i += 1024) {
        const float x = nodes[3 * i], y = nodes[3 * i + 1], z = nodes[3 * i + 2];
        const float sq = (x * x + y * y) + z * z;     // reference arithmetic
        const int pos = atomicAdd(&shc[xbucket(x)], 1);
        pts[pos] = make_float4(x, y, z, sq);
        perm[pos] = i;
    }
    __syncthreads();                                  // drains vmem before reads
    cur_g[t] = shc[t];          // inclusive bucket end (tile lookup, as r15-23)
    // bounds: 16 waves x 4 tiles each
    const int lane = t & 63, w = t >> 6;
    for (int tt = w; tt < NT; tt += 16) {
        float mn = INFINITY, mx = -INFINITY;
#pragma unroll
        for (int e = 0; e < 4; ++e) {
            const float x = pts[tt * 256 + e * 64 + lane].x;
            mn = fminf(mn, x); mx = fmaxf(mx, x);
        }
#pragma unroll
        for (int s = 1; s <= 32; s <<= 1) {
            mn = fminf(mn, __shfl_xor(mn, s));
            mx = fmaxf(mx, __shfl_xor(mx, s));
        }
        if (lane == 0) tmm_g[tt] = make_float2(mn, mx);
    }
}

// ---------------- verified helpers ----------------
__device__ __forceinline__ float bcastf(float v, int l) {
    return __int_as_float(__builtin_amdgcn_readlane(__float_as_int(v), l));
}
__device__ __forceinline__ bool lexless(float da, int ia, float db, int ib) {
    return (da < db) || ((da == db) && (ia < ib));
}
// r1-r6-verified distributed insert — overflow fallback only (~never hit).
__device__ __forceinline__ void insert_tile(bool rough, float d2, int j,
                                            float& ld, int& li,
                                            float& td, int& ti, float& td2u,
                                            int lane) {
#pragma clang fp contract(off)
    if (!__any(rough)) return;
    float dist = INFINITY;
    if (rough) dist = sqrtf(fmaxf(d2, 0.0f));
    bool done = false;
    while (true) {
        const bool pass = (!done) && rough && lexless(dist, j, td, ti);
        const u64 m = __ballot(pass);
        if (m == 0ull) break;
        const int src = __ffsll(m) - 1;
        const float dc = __shfl(dist, src);
        const int   ic = __shfl(j, src);
        if (lane == src) done = true;
        const bool gt = lexless(dc, ic, ld, li);
        const u64 gm = __ballot(gt);
        const int p = __ffsll(gm) - 1;
        const float pd = __shfl_up(ld, 1);
        const int   pi = __shfl_up(li, 1);
        if (gt) {
            if (lane == p) { ld = dc; li = ic; }
            else           { ld = pd; li = pi; }
        }
        td = __shfl(ld, 16);
        ti = __shfl(li, 16);
        td2u = td * td * 1.000001f;
    }
}

// ---------- scan body (r20-r23-verified machinery, byte-identical) ----------
__device__ __forceinline__ void scan_body(int sblock,
                                          const float4* __restrict__ pts,
                                          const int* __restrict__ perm,
                                          const int* __restrict__ cur,
                                          const float2* __restrict__ tmm_g,
                                          const float* __restrict__ nodes,
                                          float* __restrict__ out,
                                          u16* __restrict__ nbws) {
#pragma clang fp contract(off)
    const int lane = threadIdx.x & 63;
    const int wid  = threadIdx.x >> 6;
    const int tid  = threadIdx.x;
    const int rowBase = sblock * RPB;       // ORIGINAL row index, contiguous

    __shared__ float2 tmm[NT];
    __shared__ u16 buf[SW][RPW][CAP];       // 16 KB: candidate sorted-indices
    __shared__ u64 sel[SW][CAP];            // 16 KB: (distbits, orig idx) keys
    __shared__ int cnt[SW][RPW];

    if (tid < NT) tmm[tid] = tmm_g[tid];
    __syncthreads();

    float xs[RPW], ys[RPW], zs[RPW], ss[RPW];
    int tc[RPW];
#pragma unroll
    for (int r = 0; r < RPW; ++r) {
        const int row = rowBase + wid * RPW + r;
        xs[r] = nodes[3 * row];
        ys[r] = nodes[3 * row + 1];
        zs[r] = nodes[3 * row + 2];
        ss[r] = (xs[r] * xs[r] + ys[r] * ys[r]) + zs[r] * zs[r];
        int t = (cur[xbucket(xs[r])] - 1) >> 8;
        t = t - 1; t = t < 0 ? 0 : (t > NT - 3 ? NT - 3 : t);
        tc[r] = t;
    }

    // ===== tau phase: 3 local tiles per row (768 actual candidates) =====
    float rm[RPW];
#pragma unroll
    for (int r = 0; r < RPW; ++r) rm[r] = INFINITY;
#pragma unroll
    for (int r = 0; r < RPW; ++r) {
        for (int tt = 0; tt < 3; ++tt) {
            const int tb = (tc[r] + tt) * 256;
            const float4 q0 = pts[tb + lane];
            const float4 q1 = pts[tb + 64 + lane];
            const float4 q2 = pts[tb + 128 + lane];
            const float4 q3 = pts[tb + 192 + lane];
            const float d0 = (ss[r] + q0.w) - 2.0f * fmaf(zs[r], q0.z, fmaf(ys[r], q0.y, xs[r] * q0.x));
            const float d1 = (ss[r] + q1.w) - 2.0f * fmaf(zs[r], q1.z, fmaf(ys[r], q1.y, xs[r] * q1.x));
            const float d2 = (ss[r] + q2.w) - 2.0f * fmaf(zs[r], q2.z, fmaf(ys[r], q2.y, xs[r] * q2.x));
            const float d3 = (ss[r] + q3.w) - 2.0f * fmaf(zs[r], q3.z, fmaf(ys[r], q3.y, xs[r] * q3.x));
            rm[r] = fminf(rm[r], fminf(fminf(d0, d1), fminf(d2, d3)));
        }
    }
    // r12-verified bitonic sort of 64 lane-mins; tau = 17th (conservative).
    float sv[RPW];
#pragma unroll
    for (int r = 0; r < RPW; ++r) sv[r] = rm[r];
#pragma unroll
    for (int k = 2; k <= 64; k <<= 1) {
#pragma unroll
        for (int j = k >> 1; j >= 1; j >>= 1) {
            const bool keepmin = (((lane & j) == 0) == ((lane & k) == 0));
#pragma unroll
            for (int r = 0; r < RPW; ++r) {
                const float o = __shfl_xor(sv[r], j);
                sv[r] = keepmin ? fminf(sv[r], o) : fmaxf(sv[r], o);
            }
        }
    }
    float tau[RPW];
#pragma unroll
    for (int r = 0; r < RPW; ++r)   // *1.000002+eps: sqrt-tie-collapse guard
        tau[r] = fmaxf(bcastf(sv[r], 16), 0.0f) * 1.000002f + 1e-30f;

    if (lane < RPW) cnt[wid][lane] = 0;
    asm volatile("s_waitcnt lgkmcnt(0)" ::: "memory");

    // ===== screen pass: AABB-pruned tiles; append u16 sorted-idx only =====
    for (int t = 0; t < NT; ++t) {
        const float2 mm = tmm[t];
        bool kp[RPW]; bool anyk = false;
#pragma unroll
        for (int r = 0; r < RPW; ++r) {
            const float dx = fmaxf(fmaxf(mm.x - xs[r], xs[r] - mm.y), 0.0f);
            kp[r] = (dx * dx <= tau[r] * 1.00001f + 5e-5f);   // fp32-slack prune
            anyk |= kp[r];
        }
        if (!anyk) continue;        // wave-uniform skip
        const int base = t * 256;
        const float4 q0 = pts[base + lane];
        const float4 q1 = pts[base + 64 + lane];
        const float4 q2 = pts[base + 128 + lane];
        const float4 q3 = pts[base + 192 + lane];
#pragma unroll
        for (int r = 0; r < RPW; ++r) {
            if (!kp[r]) continue;
            const float d0 = (ss[r] + q0.w) - 2.0f * fmaf(zs[r], q0.z, fmaf(ys[r], q0.y, xs[r] * q0.x));
            const float d1 = (ss[r] + q1.w) - 2.0f * fmaf(zs[r], q1.z, fmaf(ys[r], q1.y, xs[r] * q1.x));
            const float d2 = (ss[r] + q2.w) - 2.0f * fmaf(zs[r], q2.z, fmaf(ys[r], q2.y, xs[r] * q2.x));
            const float d3 = (ss[r] + q3.w) - 2.0f * fmaf(zs[r], q3.z, fmaf(ys[r], q3.y, xs[r] * q3.x));
            const bool p0 = d0 <= tau[r], p1 = d1 <= tau[r];
            const bool p2 = d2 <= tau[r], p3 = d3 <= tau[r];
            if (p0 | p1 | p2 | p3) {
                if (p0) { const int o = atomicAdd(&cnt[wid][r], 1);
                          if (o < CAP) buf[wid][r][o] = (u16)(base + lane); }
                if (p1) { const int o = atomicAdd(&cnt[wid][r], 1);
                          if (o < CAP) buf[wid][r][o] = (u16)(base + 64 + lane); }
                if (p2) { const int o = atomicAdd(&cnt[wid][r], 1);
                          if (o < CAP) buf[wid][r][o] = (u16)(base + 128 + lane); }
                if (p3) { const int o = atomicAdd(&cnt[wid][r], 1);
                          if (o < CAP) buf[wid][r][o] = (u16)(base + 192 + lane); }
            }
        }
    }
    asm volatile("s_waitcnt lgkmcnt(0)" ::: "memory");

    // ===== select: recompute d2, exact lex-(dist, orig idx) rank =====
#pragma unroll
    for (int r = 0; r < RPW; ++r) {
        const int C = cnt[wid][r];
        const int row = rowBase + wid * RPW + r;
        if (C <= CAP) {                 // C >= 17 guaranteed (tau subset bound)
            for (int e = lane; e < C; e += 64) {
                const int si = (int)buf[wid][r][e];
                const float4 q = pts[si];
                const float dd = (ss[r] + q.w) - 2.0f * fmaf(zs[r], q.z, fmaf(ys[r], q.y, xs[r] * q.x));
                const float dist = sqrtf(fmaxf(dd, 0.0f));      // IEEE, as ref
                sel[wid][e] = (((u64)__float_as_uint(dist)) << 32) | (unsigned)perm[si];
            }
            asm volatile("s_waitcnt lgkmcnt(0) vmcnt(0)" ::: "memory");
            for (int e = lane; e < C; e += 64) {
                const u64 my = sel[wid][e];
                int rk = 0;
                for (int c = 0; c < C; ++c)
                    rk += (sel[wid][c] < my) ? 1 : 0;   // orig idx unique
                if (rk >= 1 && rk <= KK) {
                    if (nbws) nbws[(size_t)row * KK + rk - 1] = (u16)(my & 0xffffu);
                    else      out[(size_t)row * NN + (int)(my & 0xffffffffu)] = 1.0f;
                }
            }
            asm volatile("s_waitcnt lgkmcnt(0)" ::: "memory");  // before sel reuse
        } else {
            // Pathological overflow: verified full-scan insert, orig-idx keys.
            float ld = INFINITY; int li = 0x7fffffff;
            float td = INFINITY; int ti = 0x7fffffff; float t2 = INFINITY;
            for (int tt = 0; tt < NN / 64; ++tt) {
                const int j = tt * 64 + lane;
                const float4 q = pts[j];
                const int oi = perm[j];
                const float dd = (ss[r] + q.w) - 2.0f * fmaf(zs[r], q.z, fmaf(ys[r], q.y, xs[r] * q.x));
                insert_tile(dd <= t2, dd, oi, ld, li, td, ti, t2, lane);
            }
            if (lane >= 1 && lane <= KK) {
                if (nbws) nbws[(size_t)row * KK + lane - 1] = (u16)li;
                else      out[(size_t)row * NN + li] = 1.0f;
            }
        }
    }
}

// ===== k_mega: 1024 scan + 1024 fill blocks, 1:1 parity interleave (b&1) ====
// Empirically the best selector (r23=262 vs r21 %3=304, r25 b&8=333).
// 4096 scan waves + 4096 fill waves = device wave capacity.
__global__ __launch_bounds__(256) void k_mega(const float4* __restrict__ pts,
                                              const int* __restrict__ perm,
                                              const int* __restrict__ cur,
                                              const float2* __restrict__ tmm_g,
                                              const float* __restrict__ nodes,
                                              float* __restrict__ out,
                                              u16* __restrict__ nbws) {
    const int b = blockIdx.x;
    if (b & 1) {
        // ---- fill block: whole output, NT streaming (r19-r23-verified) ----
        const int fidx = b >> 1;                      // 0..1023
        const int tid = fidx * 256 + threadIdx.x;
        const int nthreads = MEGA_FILL * 256;
        f32x4* ob = (f32x4*)out;
        const f32x4 z4 = {0.f, 0.f, 0.f, 0.f};
#pragma unroll 4
        for (int k = 0; k < (NN * (NN / 4)) / nthreads; ++k)   // 256 iterations
            __builtin_nontemporal_store(z4, ob + (size_t)k * nthreads + tid);
    } else {
        scan_body(b >> 1, pts, perm, cur, tmm_g, nodes, nullptr, nbws);
    }
}

// ============ k_ones: stamp the 262144 ones (stream-ordered after mega) =====
__global__ __launch_bounds__(256) void ones_kernel(const u16* __restrict__ nbws,
                                                   float* __restrict__ out) {
    const int t = blockIdx.x * 256 + threadIdx.x;     // t < NN*KK
    const int row = t >> 4;
    out[(size_t)row * NN + nbws[t]] = 1.0f;
}

// ---------------- fallback (ws too small): serial r20 path ----------------
__global__ __launch_bounds__(256) void fill_zero_full(f32x4* __restrict__ ob) {
    const int tid = blockIdx.x * 256 + threadIdx.x;
    const int nthreads = 2048 * 256;
    const f32x4 z4 = {0.f, 0.f, 0.f, 0.f};
#pragma unroll 4
    for (int k = 0; k < (NN * (NN / 4)) / nthreads; ++k)
        __builtin_nontemporal_store(z4, ob + (size_t)k * nthreads + tid);
}

__global__ __launch_bounds__(256) void knn_scan_direct(const float4* __restrict__ pts,
                                                       const int* __restrict__ perm,
                                                       const int* __restrict__ cur,
                                                       const float2* __restrict__ tmm_g,
                                                       const float* __restrict__ nodes,
                                                       float* __restrict__ out) {
    scan_body(blockIdx.x, pts, perm, cur, tmm_g, nodes, out, nullptr);
}

extern "C" void kernel_launch(void* const* d_in, const int* in_sizes, int n_in,
                              void* d_out, int out_size, void* d_ws, size_t ws_size,
                              hipStream_t stream) {
    const float* nodes = (const float*)d_in[0];
    float* out = (float*)d_out;
    (void)in_sizes; (void)n_in; (void)out_size;

    char* ws = (char*)d_ws;
    float4* pts  = (float4*)(ws + WS_PTS);
    int*    perm = (int*)   (ws + WS_PERM);
    int*    cur  = (int*)   (ws + WS_CUR);
    float2* tmm  = (float2*)(ws + WS_TMM);
    u16*    nbws = (u16*)   (ws + WS_NB);

    hipLaunchKernelGGL(k_sort, dim3(1), dim3(1024), 0, stream,
                       nodes, pts, perm, cur, tmm);

    if (ws_size >= WS_NEED) {
        hipLaunchKernelGGL(k_mega, dim3(2 * SCAN_BLOCKS), dim3(256), 0, stream,
                           pts, perm, cur, tmm, nodes, out, nbws);
        hipLaunchKernelGGL(ones_kernel, dim3(NN * KK / 256), dim3(256), 0, stream,
                           nbws, out);
    } else {
        hipLaunchKernelGGL(fill_zero_full, dim3(2048), dim3(256), 0, stream,
                           (f32x4*)out);
        hipLaunchKernelGGL(knn_scan_direct, dim3(SCAN_BLOCKS), dim3(256), 0, stream,
                           pts, perm, cur, tmm, nodes, out);
    }
}